// Round 2
// baseline (170.251 us; speedup 1.0000x reference)
//
#include <hip/hip_runtime.h>
#include <math.h>

#define N_NODES 100000
#define N_EDGES 1600000

// ---------------------------------------------------------------------------
// Pack pos (3f) + node_feats (9f) into one 64B-aligned 16-float row per node:
//   floats 0..2 = pos, float 3 = f0, floats 4..11 = f1..f8, 12..15 unused.
// Turns 15 divergent scalar gathers/edge into 4 divergent dwordx4 gathers.
// ---------------------------------------------------------------------------
__global__ __launch_bounds__(256) void pack_kernel(
    const float* __restrict__ pos,
    const float* __restrict__ feats,
    float4* __restrict__ packed)          // [N_NODES * 4] float4 rows
{
    const int i = blockIdx.x * blockDim.x + threadIdx.x;
    if (i >= N_NODES) return;
    const float* p = pos + 3 * i;
    const float* f = feats + 9 * i;
    packed[4 * i + 0] = make_float4(p[0], p[1], p[2], f[0]);
    packed[4 * i + 1] = make_float4(f[1], f[2], f[3], f[4]);
    packed[4 * i + 2] = make_float4(f[5], f[6], f[7], f[8]);
    // row word 3 never read — left unwritten
}

__device__ __forceinline__ float edge_msg(
    const float4 a, const float4 b, const float4 c, const float4 pd,
    const float* __restrict__ sW1, const float* __restrict__ sW2)
{
    const float vx = pd.x - a.x;
    const float vy = pd.y - a.y;
    const float vz = pd.z - a.z;

    const float r   = sqrtf(vx * vx + vy * vy + vz * vz);
    const float inv = 1.0f / (r + 1e-12f);
    const float x = vx * inv, y = vy * inv, z = vz * inv;

    // spherical harmonics lmax=2 (sh0==1 folded into path_s)
    const float s3  = 1.7320508075688772f;
    const float s5  = 2.23606797749979f;
    const float s15 = 3.872983346207417f;
    const float sh1 = s3 * x;
    const float sh2 = s3 * y;
    const float sh3 = s3 * z;
    const float sh4 = s15 * x * z;
    const float sh5 = s15 * x * y;
    const float sh6 = s5 * (y * y - 0.5f * (x * x + z * z));
    const float sh7 = s15 * y * z;
    const float sh8 = 0.5f * s15 * (z * z - x * x);

    // radial basis: q = r*(11/5); active bins k-1, k with d0 in [0,1)
    const float q = r * 2.2f;
    const int   k = (int)floorf(q);
    int   b0 = k - 1, b1 = k;
    const float d0 = q - (float)k;
    const float d1 = d0 - 1.0f;
    const float A = 8.43357307f;              // 1.14136 * e^2
    float e0 = 0.0f, e1 = 0.0f;
    if (b0 >= 0 && b0 < 10) {
        const float dd = d0 * d0;
        if (dd < 1.0f) e0 = A * expf(-1.0f / (1.0f - dd));
    }
    if (b1 >= 0 && b1 < 10) {
        const float dd = d1 * d1;
        if (dd < 1.0f) e1 = A * expf(-1.0f / (1.0f - dd));
    }
    b0 = (b0 >= 0 && b0 < 10) ? b0 : 0;
    b1 = (b1 >= 0 && b1 < 10) ? b1 : 0;

    const float* w1r0 = sW1 + b0 * 17;
    const float* w1r1 = sW1 + b1 * 17;
    float acc0 = 0.0f, acc1 = 0.0f, acc2 = 0.0f;
#pragma unroll
    for (int j = 0; j < 16; ++j) {
        const float hj = fmaxf(e0 * w1r0[j] + e1 * w1r1[j], 0.0f);
        acc0 = fmaf(hj, sW2[j * 3 + 0], acc0);
        acc1 = fmaf(hj, sW2[j * 3 + 1], acc1);
        acc2 = fmaf(hj, sW2[j * 3 + 2], acc2);
    }

    const float path_s = a.w;
    const float path_p = (b.x * sh1 + b.y * sh2 + b.z * sh3) * 0.5773502691896258f;
    const float path_d = (b.w * sh4 + c.x * sh5 + c.y * sh6
                        + c.z * sh7 + c.w * sh8) * 0.4472135954999579f;

    const float FINAL = 0.06454972243679028f;  // sqrt(2)/(4*sqrt(3)*sqrt(10))
    return (acc0 * path_s + acc1 * path_p + acc2 * path_d) * FINAL;
}

// 4 edges per thread: int4 index loads, 4 independent gather chains for MLP.
__global__ __launch_bounds__(256, 4) void edge_kernel4(
    const float4* __restrict__ packed,
    const float* __restrict__ W1,
    const float* __restrict__ W2,
    const int4* __restrict__ src4,        // [N_EDGES/4]
    const int4* __restrict__ dst4,
    float* __restrict__ out)
{
    __shared__ float sW1[10 * 17];
    __shared__ float sW2[16 * 3];
    const int t = threadIdx.x;
    if (t < 160) sW1[(t >> 4) * 17 + (t & 15)] = W1[t];
    if (t < 48)  sW2[t] = W2[t];
    __syncthreads();

    const int tid = blockIdx.x * blockDim.x + t;
    if (tid >= N_EDGES / 4) return;

    const int4 s = src4[tid];
    const int4 d = dst4[tid];
    const int si[4] = { s.x, s.y, s.z, s.w };
    const int di[4] = { d.x, d.y, d.z, d.w };

    // issue all gathers up front — compiler interleaves the 16 dwordx4 loads
    float4 ra[4], rb[4], rc[4], rd[4];
#pragma unroll
    for (int i = 0; i < 4; ++i) {
        const float4* rs = packed + 4 * si[i];
        ra[i] = rs[0];
        rb[i] = rs[1];
        rc[i] = rs[2];
        rd[i] = packed[4 * di[i]];
    }

#pragma unroll
    for (int i = 0; i < 4; ++i) {
        const float msg = edge_msg(ra[i], rb[i], rc[i], rd[i], sW1, sW2);
        unsafeAtomicAdd(out + di[i], msg);
    }
}

// Fallback (ws too small): round-1 style direct-gather kernel.
__global__ __launch_bounds__(256) void edge_kernel_direct(
    const float* __restrict__ pos,
    const float* __restrict__ node_feats,
    const float* __restrict__ W1,
    const float* __restrict__ W2,
    const int*   __restrict__ edge_src,
    const int*   __restrict__ edge_dst,
    float* __restrict__ out)
{
    __shared__ float sW1[10 * 17];
    __shared__ float sW2[16 * 3];
    const int t = threadIdx.x;
    if (t < 160) sW1[(t >> 4) * 17 + (t & 15)] = W1[t];
    if (t < 48)  sW2[t] = W2[t];
    __syncthreads();

    const int e = blockIdx.x * blockDim.x + t;
    if (e >= N_EDGES) return;

    const int src = edge_src[e];
    const int dst = edge_dst[e];
    const float* ps = pos + 3 * src;
    const float* pd = pos + 3 * dst;
    const float* xf = node_feats + 9 * src;
    const float4 a = make_float4(ps[0], ps[1], ps[2], xf[0]);
    const float4 b = make_float4(xf[1], xf[2], xf[3], xf[4]);
    const float4 c = make_float4(xf[5], xf[6], xf[7], xf[8]);
    const float4 pdv = make_float4(pd[0], pd[1], pd[2], 0.0f);
    const float msg = edge_msg(a, b, c, pdv, sW1, sW2);
    unsafeAtomicAdd(out + dst, msg);
}

extern "C" void kernel_launch(void* const* d_in, const int* in_sizes, int n_in,
                              void* d_out, int out_size, void* d_ws, size_t ws_size,
                              hipStream_t stream) {
    const float* pos        = (const float*)d_in[0];
    const float* node_feats = (const float*)d_in[1];
    const float* W1         = (const float*)d_in[2];
    const float* W2         = (const float*)d_in[3];
    const int*   edge_src   = (const int*)d_in[4];
    const int*   edge_dst   = (const int*)d_in[5];
    float* out = (float*)d_out;

    hipMemsetAsync(out, 0, N_NODES * sizeof(float), stream);

    const size_t pack_bytes = (size_t)N_NODES * 4 * sizeof(float4); // 6.4 MB
    if (ws_size >= pack_bytes) {
        float4* packed = (float4*)d_ws;
        pack_kernel<<<(N_NODES + 255) / 256, 256, 0, stream>>>(pos, node_feats, packed);
        edge_kernel4<<<(N_EDGES / 4 + 255) / 256, 256, 0, stream>>>(
            packed, W1, W2, (const int4*)edge_src, (const int4*)edge_dst, out);
    } else {
        edge_kernel_direct<<<(N_EDGES + 255) / 256, 256, 0, stream>>>(
            pos, node_feats, W1, W2, edge_src, edge_dst, out);
    }
}

// Round 3
// 162.733 us; speedup vs baseline: 1.0462x; 1.0462x over previous
//
#include <hip/hip_runtime.h>
#include <math.h>

#define N_NODES 100000
#define N_EDGES 1600000
#define NREP 8

// ---------------------------------------------------------------------------
// Two packed tables (both L2-friendly, unlike one 6.4MB table which thrashed
// the 4MB per-XCD L2 in round 2):
//   posw[i]   = {pos.x, pos.y, pos.z, f0}          1.6 MB  (src + dst gather)
//   featsw[i] = {f1..f4},{f5..f8} (2 float4)       3.2 MB  (src gather only)
// ---------------------------------------------------------------------------
__global__ __launch_bounds__(256) void pack_kernel(
    const float* __restrict__ pos,
    const float* __restrict__ feats,
    float4* __restrict__ posw,            // [N_NODES]
    float4* __restrict__ featsw)          // [N_NODES*2]
{
    const int i = blockIdx.x * blockDim.x + threadIdx.x;
    if (i >= N_NODES) return;
    const float* p = pos + 3 * i;
    const float* f = feats + 9 * i;
    posw[i]           = make_float4(p[0], p[1], p[2], f[0]);
    featsw[2 * i + 0] = make_float4(f[1], f[2], f[3], f[4]);
    featsw[2 * i + 1] = make_float4(f[5], f[6], f[7], f[8]);
}

__device__ __forceinline__ float edge_msg(
    const float4 a, const float4 b, const float4 c, const float4 pd,
    const float* __restrict__ sW1, const float* __restrict__ sW2)
{
    const float vx = pd.x - a.x;
    const float vy = pd.y - a.y;
    const float vz = pd.z - a.z;

    const float r   = sqrtf(vx * vx + vy * vy + vz * vz);
    const float inv = 1.0f / (r + 1e-12f);
    const float x = vx * inv, y = vy * inv, z = vz * inv;

    const float s3  = 1.7320508075688772f;
    const float s5  = 2.23606797749979f;
    const float s15 = 3.872983346207417f;
    const float sh1 = s3 * x;
    const float sh2 = s3 * y;
    const float sh3 = s3 * z;
    const float sh4 = s15 * x * z;
    const float sh5 = s15 * x * y;
    const float sh6 = s5 * (y * y - 0.5f * (x * x + z * z));
    const float sh7 = s15 * y * z;
    const float sh8 = 0.5f * s15 * (z * z - x * x);

    // radial basis: q = r*(11/5); active bins k-1, k
    const float q = r * 2.2f;
    const int   k = (int)floorf(q);
    int   b0 = k - 1, b1 = k;
    const float d0 = q - (float)k;
    const float d1 = d0 - 1.0f;
    const float A = 8.43357307f;              // 1.14136 * e^2
    float e0 = 0.0f, e1 = 0.0f;
    if (b0 >= 0 && b0 < 10) {
        const float dd = d0 * d0;
        if (dd < 1.0f) e0 = A * expf(-1.0f / (1.0f - dd));
    }
    if (b1 >= 0 && b1 < 10) {
        const float dd = d1 * d1;
        if (dd < 1.0f) e1 = A * expf(-1.0f / (1.0f - dd));
    }
    b0 = (b0 >= 0 && b0 < 10) ? b0 : 0;
    b1 = (b1 >= 0 && b1 < 10) ? b1 : 0;

    const float* w1r0 = sW1 + b0 * 17;
    const float* w1r1 = sW1 + b1 * 17;
    float acc0 = 0.0f, acc1 = 0.0f, acc2 = 0.0f;
#pragma unroll
    for (int j = 0; j < 16; ++j) {
        const float hj = fmaxf(e0 * w1r0[j] + e1 * w1r1[j], 0.0f);
        acc0 = fmaf(hj, sW2[j * 3 + 0], acc0);
        acc1 = fmaf(hj, sW2[j * 3 + 1], acc1);
        acc2 = fmaf(hj, sW2[j * 3 + 2], acc2);
    }

    const float path_s = a.w;
    const float path_p = (b.x * sh1 + b.y * sh2 + b.z * sh3) * 0.5773502691896258f;
    const float path_d = (b.w * sh4 + c.x * sh5 + c.y * sh6
                        + c.z * sh7 + c.w * sh8) * 0.4472135954999579f;

    const float FINAL = 0.06454972243679028f;  // sqrt(2)/(4*sqrt(3)*sqrt(10))
    return (acc0 * path_s + acc1 * path_p + acc2 * path_d) * FINAL;
}

// 2 edges/thread; atomics spread across NREP output replicas to cut
// per-cache-line RMW serialization at the coherence point.
__global__ __launch_bounds__(256, 4) void edge_kernel2(
    const float4* __restrict__ posw,
    const float4* __restrict__ featsw,
    const float* __restrict__ W1,
    const float* __restrict__ W2,
    const int2* __restrict__ src2,        // [N_EDGES/2]
    const int2* __restrict__ dst2,
    float* __restrict__ reps)             // [NREP][N_NODES]
{
    __shared__ float sW1[10 * 17];
    __shared__ float sW2[16 * 3];
    const int t = threadIdx.x;
    if (t < 160) sW1[(t >> 4) * 17 + (t & 15)] = W1[t];
    if (t < 48)  sW2[t] = W2[t];
    __syncthreads();

    const int tid = blockIdx.x * blockDim.x + t;
    if (tid >= N_EDGES / 2) return;

    const int2 s = src2[tid];
    const int2 d = dst2[tid];

    // issue both edges' gathers up front
    const float4 a0 = posw[s.x];
    const float4 b0 = featsw[2 * s.x + 0];
    const float4 c0 = featsw[2 * s.x + 1];
    const float4 p0 = posw[d.x];
    const float4 a1 = posw[s.y];
    const float4 b1 = featsw[2 * s.y + 0];
    const float4 c1 = featsw[2 * s.y + 1];
    const float4 p1 = posw[d.y];

    float* rep = reps + (size_t)(blockIdx.x & (NREP - 1)) * N_NODES;

    const float m0 = edge_msg(a0, b0, c0, p0, sW1, sW2);
    unsafeAtomicAdd(rep + d.x, m0);
    const float m1 = edge_msg(a1, b1, c1, p1, sW1, sW2);
    unsafeAtomicAdd(rep + d.y, m1);
}

__global__ __launch_bounds__(256) void reduce_kernel(
    const float* __restrict__ reps, float* __restrict__ out)
{
    const int i = blockIdx.x * blockDim.x + threadIdx.x;
    if (i >= N_NODES) return;
    float sum = 0.0f;
#pragma unroll
    for (int k = 0; k < NREP; ++k) sum += reps[(size_t)k * N_NODES + i];
    out[i] = sum;
}

// Fallback if ws is too small: round-1 direct kernel.
__global__ __launch_bounds__(256) void edge_kernel_direct(
    const float* __restrict__ pos,
    const float* __restrict__ node_feats,
    const float* __restrict__ W1,
    const float* __restrict__ W2,
    const int*   __restrict__ edge_src,
    const int*   __restrict__ edge_dst,
    float* __restrict__ out)
{
    __shared__ float sW1[10 * 17];
    __shared__ float sW2[16 * 3];
    const int t = threadIdx.x;
    if (t < 160) sW1[(t >> 4) * 17 + (t & 15)] = W1[t];
    if (t < 48)  sW2[t] = W2[t];
    __syncthreads();

    const int e = blockIdx.x * blockDim.x + t;
    if (e >= N_EDGES) return;

    const int src = edge_src[e];
    const int dst = edge_dst[e];
    const float* ps = pos + 3 * src;
    const float* pd = pos + 3 * dst;
    const float* xf = node_feats + 9 * src;
    const float4 a = make_float4(ps[0], ps[1], ps[2], xf[0]);
    const float4 b = make_float4(xf[1], xf[2], xf[3], xf[4]);
    const float4 c = make_float4(xf[5], xf[6], xf[7], xf[8]);
    const float4 pdv = make_float4(pd[0], pd[1], pd[2], 0.0f);
    const float msg = edge_msg(a, b, c, pdv, sW1, sW2);
    unsafeAtomicAdd(out + dst, msg);
}

extern "C" void kernel_launch(void* const* d_in, const int* in_sizes, int n_in,
                              void* d_out, int out_size, void* d_ws, size_t ws_size,
                              hipStream_t stream) {
    const float* pos        = (const float*)d_in[0];
    const float* node_feats = (const float*)d_in[1];
    const float* W1         = (const float*)d_in[2];
    const float* W2         = (const float*)d_in[3];
    const int*   edge_src   = (const int*)d_in[4];
    const int*   edge_dst   = (const int*)d_in[5];
    float* out = (float*)d_out;

    const size_t posw_bytes   = (size_t)N_NODES * sizeof(float4);       // 1.6 MB
    const size_t featsw_bytes = (size_t)N_NODES * 2 * sizeof(float4);   // 3.2 MB
    const size_t reps_bytes   = (size_t)NREP * N_NODES * sizeof(float); // 3.2 MB
    const size_t need = posw_bytes + featsw_bytes + reps_bytes;

    if (ws_size >= need) {
        float4* posw   = (float4*)d_ws;
        float4* featsw = (float4*)((char*)d_ws + posw_bytes);
        float*  reps   = (float*)((char*)d_ws + posw_bytes + featsw_bytes);

        hipMemsetAsync(reps, 0, reps_bytes, stream);
        pack_kernel<<<(N_NODES + 255) / 256, 256, 0, stream>>>(pos, node_feats, posw, featsw);
        edge_kernel2<<<(N_EDGES / 2 + 255) / 256, 256, 0, stream>>>(
            posw, featsw, W1, W2, (const int2*)edge_src, (const int2*)edge_dst, reps);
        reduce_kernel<<<(N_NODES + 255) / 256, 256, 0, stream>>>(reps, out);
    } else {
        hipMemsetAsync(out, 0, N_NODES * sizeof(float), stream);
        edge_kernel_direct<<<(N_EDGES + 255) / 256, 256, 0, stream>>>(
            pos, node_feats, W1, W2, edge_src, edge_dst, out);
    }
}

// Round 4
// 142.386 us; speedup vs baseline: 1.1957x; 1.1429x over previous
//
#include <hip/hip_runtime.h>
#include <math.h>

#define N_NODES 100000
#define N_EDGES 1600000

#define BUCKETS 8
#define SUBS 64
#define BUCKET_NODES (N_NODES / BUCKETS)   // 12500 -> 50 KB LDS
#define SLICE (N_EDGES / SUBS)             // 25000 edges per slice

// ---------------------------------------------------------------------------
// Packed gather tables (fit per-XCD L2 individually):
//   posw[i]   = {pos.xyz, f0}     1.6 MB
//   featsw[i] = {f1..f8}          3.2 MB
// ---------------------------------------------------------------------------
__global__ __launch_bounds__(256) void pack_kernel(
    const float* __restrict__ pos,
    const float* __restrict__ feats,
    float4* __restrict__ posw,
    float4* __restrict__ featsw)
{
    const int i = blockIdx.x * blockDim.x + threadIdx.x;
    if (i >= N_NODES) return;
    const float* p = pos + 3 * i;
    const float* f = feats + 9 * i;
    posw[i]           = make_float4(p[0], p[1], p[2], f[0]);
    featsw[2 * i + 0] = make_float4(f[1], f[2], f[3], f[4]);
    featsw[2 * i + 1] = make_float4(f[5], f[6], f[7], f[8]);
}

__device__ __forceinline__ float edge_msg(
    const float4 a, const float4 b, const float4 c, const float4 pd,
    const float* __restrict__ sW1, const float* __restrict__ sW2)
{
    const float vx = pd.x - a.x;
    const float vy = pd.y - a.y;
    const float vz = pd.z - a.z;

    const float r   = sqrtf(vx * vx + vy * vy + vz * vz);
    const float inv = 1.0f / (r + 1e-12f);
    const float x = vx * inv, y = vy * inv, z = vz * inv;

    const float s3  = 1.7320508075688772f;
    const float s5  = 2.23606797749979f;
    const float s15 = 3.872983346207417f;
    const float sh1 = s3 * x;
    const float sh2 = s3 * y;
    const float sh3 = s3 * z;
    const float sh4 = s15 * x * z;
    const float sh5 = s15 * x * y;
    const float sh6 = s5 * (y * y - 0.5f * (x * x + z * z));
    const float sh7 = s15 * y * z;
    const float sh8 = 0.5f * s15 * (z * z - x * x);

    // radial basis: q = r*(11/5); active bins k-1, k
    const float q = r * 2.2f;
    const int   k = (int)floorf(q);
    int   b0 = k - 1, b1 = k;
    const float d0 = q - (float)k;
    const float d1 = d0 - 1.0f;
    const float A = 8.43357307f;              // 1.14136 * e^2
    float e0 = 0.0f, e1 = 0.0f;
    if (b0 >= 0 && b0 < 10) {
        const float dd = d0 * d0;
        if (dd < 1.0f) e0 = A * expf(-1.0f / (1.0f - dd));
    }
    if (b1 >= 0 && b1 < 10) {
        const float dd = d1 * d1;
        if (dd < 1.0f) e1 = A * expf(-1.0f / (1.0f - dd));
    }
    b0 = (b0 >= 0 && b0 < 10) ? b0 : 0;
    b1 = (b1 >= 0 && b1 < 10) ? b1 : 0;

    const float* w1r0 = sW1 + b0 * 17;
    const float* w1r1 = sW1 + b1 * 17;
    float acc0 = 0.0f, acc1 = 0.0f, acc2 = 0.0f;
#pragma unroll
    for (int j = 0; j < 16; ++j) {
        const float hj = fmaxf(e0 * w1r0[j] + e1 * w1r1[j], 0.0f);
        acc0 = fmaf(hj, sW2[j * 3 + 0], acc0);
        acc1 = fmaf(hj, sW2[j * 3 + 1], acc1);
        acc2 = fmaf(hj, sW2[j * 3 + 2], acc2);
    }

    const float path_s = a.w;
    const float path_p = (b.x * sh1 + b.y * sh2 + b.z * sh3) * 0.5773502691896258f;
    const float path_d = (b.w * sh4 + c.x * sh5 + c.y * sh6
                        + c.z * sh7 + c.w * sh8) * 0.4472135954999579f;

    const float FINAL = 0.06454972243679028f;  // sqrt(2)/(4*sqrt(3)*sqrt(10))
    return (acc0 * path_s + acc1 * path_p + acc2 * path_d) * FINAL;
}

// Phase 1: per-edge message, coalesced write. ZERO global atomics.
// This dispatch's duration is the atomic-wall discriminator.
__global__ __launch_bounds__(256) void msg_kernel(
    const float4* __restrict__ posw,
    const float4* __restrict__ featsw,
    const float* __restrict__ W1,
    const float* __restrict__ W2,
    const int* __restrict__ edge_src,
    const int* __restrict__ edge_dst,
    float* __restrict__ msg)
{
    __shared__ float sW1[10 * 17];
    __shared__ float sW2[16 * 3];
    const int t = threadIdx.x;
    if (t < 160) sW1[(t >> 4) * 17 + (t & 15)] = W1[t];
    if (t < 48)  sW2[t] = W2[t];
    __syncthreads();

    const int e = blockIdx.x * blockDim.x + t;
    if (e >= N_EDGES) return;

    const int s = edge_src[e];
    const int d = edge_dst[e];
    const float4 a = posw[s];
    const float4 b = featsw[2 * s + 0];
    const float4 c = featsw[2 * s + 1];
    const float4 p = posw[d];
    msg[e] = edge_msg(a, b, c, p, sW1, sW2);
}

// Phase 2: block (bucket b, slice s) streams slice s of (dst, msg) coalesced,
// accumulates in-bucket nodes into a 50KB LDS array via LDS atomics,
// writes its slab coalesced. No global atomics.
__global__ __launch_bounds__(256) void scatter_kernel(
    const int* __restrict__ edge_dst,
    const float* __restrict__ msg,
    float* __restrict__ slabs)            // [BUCKETS][SUBS][BUCKET_NODES]
{
    __shared__ float acc[BUCKET_NODES];   // 50 KB
    const int b = blockIdx.x >> 6;        // / SUBS
    const int s = blockIdx.x & (SUBS - 1);
    const int base = b * BUCKET_NODES;
    const int t = threadIdx.x;

    for (int i = t; i < BUCKET_NODES; i += 256) acc[i] = 0.0f;
    __syncthreads();

    const int e0 = s * SLICE;
    const int4*   d4 = (const int4*)(edge_dst + e0);
    const float4* m4 = (const float4*)(msg + e0);
    for (int i = t; i < SLICE / 4; i += 256) {
        const int4   d = d4[i];
        const float4 m = m4[i];
        if ((unsigned)(d.x - base) < (unsigned)BUCKET_NODES) atomicAdd(&acc[d.x - base], m.x);
        if ((unsigned)(d.y - base) < (unsigned)BUCKET_NODES) atomicAdd(&acc[d.y - base], m.y);
        if ((unsigned)(d.z - base) < (unsigned)BUCKET_NODES) atomicAdd(&acc[d.z - base], m.z);
        if ((unsigned)(d.w - base) < (unsigned)BUCKET_NODES) atomicAdd(&acc[d.w - base], m.w);
    }
    __syncthreads();

    float* slab = slabs + ((size_t)blockIdx.x) * BUCKET_NODES;
    for (int i = t; i < BUCKET_NODES; i += 256) slab[i] = acc[i];
}

// Phase 3: out[n] = sum over SUBS slabs of its bucket. Coalesced per k-step.
__global__ __launch_bounds__(256) void reduce_kernel(
    const float* __restrict__ slabs, float* __restrict__ out)
{
    const int n = blockIdx.x * blockDim.x + threadIdx.x;
    if (n >= N_NODES) return;
    const int b = n / BUCKET_NODES;
    const int i = n - b * BUCKET_NODES;
    const float* sl = slabs + (size_t)b * SUBS * BUCKET_NODES + i;
    float sum = 0.0f;
#pragma unroll
    for (int k = 0; k < SUBS; ++k) sum += sl[(size_t)k * BUCKET_NODES];
    out[n] = sum;
}

// Fallback (ws too small): direct atomic kernel.
__global__ __launch_bounds__(256) void edge_kernel_direct(
    const float* __restrict__ pos,
    const float* __restrict__ node_feats,
    const float* __restrict__ W1,
    const float* __restrict__ W2,
    const int*   __restrict__ edge_src,
    const int*   __restrict__ edge_dst,
    float* __restrict__ out)
{
    __shared__ float sW1[10 * 17];
    __shared__ float sW2[16 * 3];
    const int t = threadIdx.x;
    if (t < 160) sW1[(t >> 4) * 17 + (t & 15)] = W1[t];
    if (t < 48)  sW2[t] = W2[t];
    __syncthreads();

    const int e = blockIdx.x * blockDim.x + t;
    if (e >= N_EDGES) return;

    const int src = edge_src[e];
    const int dst = edge_dst[e];
    const float* ps = pos + 3 * src;
    const float* pd = pos + 3 * dst;
    const float* xf = node_feats + 9 * src;
    const float4 a = make_float4(ps[0], ps[1], ps[2], xf[0]);
    const float4 b = make_float4(xf[1], xf[2], xf[3], xf[4]);
    const float4 c = make_float4(xf[5], xf[6], xf[7], xf[8]);
    const float4 pdv = make_float4(pd[0], pd[1], pd[2], 0.0f);
    const float m = edge_msg(a, b, c, pdv, sW1, sW2);
    unsafeAtomicAdd(out + dst, m);
}

extern "C" void kernel_launch(void* const* d_in, const int* in_sizes, int n_in,
                              void* d_out, int out_size, void* d_ws, size_t ws_size,
                              hipStream_t stream) {
    const float* pos        = (const float*)d_in[0];
    const float* node_feats = (const float*)d_in[1];
    const float* W1         = (const float*)d_in[2];
    const float* W2         = (const float*)d_in[3];
    const int*   edge_src   = (const int*)d_in[4];
    const int*   edge_dst   = (const int*)d_in[5];
    float* out = (float*)d_out;

    const size_t posw_bytes   = (size_t)N_NODES * sizeof(float4);                  // 1.6 MB
    const size_t featsw_bytes = (size_t)N_NODES * 2 * sizeof(float4);              // 3.2 MB
    const size_t msg_bytes    = (size_t)N_EDGES * sizeof(float);                   // 6.4 MB
    const size_t slab_bytes   = (size_t)BUCKETS * SUBS * BUCKET_NODES * sizeof(float); // 25.6 MB
    const size_t need = posw_bytes + featsw_bytes + msg_bytes + slab_bytes;

    if (ws_size >= need) {
        char* w = (char*)d_ws;
        float4* posw   = (float4*)w;                      w += posw_bytes;
        float4* featsw = (float4*)w;                      w += featsw_bytes;
        float*  msg    = (float*)w;                       w += msg_bytes;
        float*  slabs  = (float*)w;

        pack_kernel<<<(N_NODES + 255) / 256, 256, 0, stream>>>(pos, node_feats, posw, featsw);
        msg_kernel<<<(N_EDGES + 255) / 256, 256, 0, stream>>>(
            posw, featsw, W1, W2, edge_src, edge_dst, msg);
        scatter_kernel<<<BUCKETS * SUBS, 256, 0, stream>>>(edge_dst, msg, slabs);
        reduce_kernel<<<(N_NODES + 255) / 256, 256, 0, stream>>>(slabs, out);
    } else {
        hipMemsetAsync(out, 0, N_NODES * sizeof(float), stream);
        edge_kernel_direct<<<(N_EDGES + 255) / 256, 256, 0, stream>>>(
            pos, node_feats, W1, W2, edge_src, edge_dst, out);
    }
}